// Round 7
// baseline (126.331 us; speedup 1.0000x reference)
//
#include <hip/hip_runtime.h>
#include <hip/hip_bf16.h>

// Sizes
#define Bb 16
#define Gg 2048
#define Dd 2048
#define XS 4097   // G + D + 1
#define EPSf 1e-5f
#define CEXP (-0.72134752044448170368f)   // -gamma * log2(e), gamma = 0.5

typedef unsigned int u32;
typedef __attribute__((ext_vector_type(8))) short bf16x8;
typedef __attribute__((ext_vector_type(4))) float f32x4;

union U16 { uint4 u; bf16x8 v; };

__device__ inline float fast_exp2(float x) {
#if __has_builtin(__builtin_amdgcn_exp2f)
  return __builtin_amdgcn_exp2f(x);
#else
  return exp2f(x);
#endif
}

// pack two f32 into one u32 of 2 bf16 (truncation): low half from a, high from b
__device__ inline u32 pk2(float a, float b) {
  return __builtin_amdgcn_perm(__float_as_uint(b), __float_as_uint(a), 0x07060302u);
}
__device__ inline float bftrunc(float a) {
  return __uint_as_float(__float_as_uint(a) & 0xFFFF0000u);
}

// split 8 floats into hi/lo bf16x8 fragments
__device__ inline void split8(const float* f, U16& hi, U16& lo) {
  u32 h[4], l[4];
  #pragma unroll
  for (int p = 0; p < 4; ++p) {
    float a = f[2 * p], b = f[2 * p + 1];
    h[p] = pk2(a, b);
    l[p] = pk2(a - bftrunc(a), b - bftrunc(b));
  }
  hi.u = make_uint4(h[0], h[1], h[2], h[3]);
  lo.u = make_uint4(l[0], l[1], l[2], l[3]);
}

__device__ inline float wred(float v) {
  #pragma unroll
  for (int o = 32; o > 0; o >>= 1) v += __shfl_xor(v, o, 64);
  return v;
}

// ---------------- K0: split weights into MFMA-frag-linear bf16 hi/lo ------
__global__ __launch_bounds__(256) void k_split(const float* __restrict__ Wrbf,
                                               const float* __restrict__ Wdg,
                                               u32* __restrict__ Rhi, u32* __restrict__ Rlo,
                                               u32* __restrict__ Dhi, u32* __restrict__ Dlo) {
  int c = blockIdx.x * 256 + threadIdx.x;   // 270336 total
  const float* src;
  u32 *dhi, *dlo;
  if (c < 8192) {
    int h = c >> 12, ks = (c >> 6) & 63, l = c & 63;
    src = Wrbf + (h * 16 + (l & 15)) * Gg + ks * 32 + (l >> 4) * 8;
    dhi = Rhi + (size_t)c * 4; dlo = Rlo + (size_t)c * 4;
  } else {
    int cc = c - 8192;
    int nf = cc >> 12, ks = (cc >> 6) & 63, l = cc & 63;
    src = Wdg + (size_t)(nf * 16 + (l & 15)) * Gg + ks * 32 + (l >> 4) * 8;
    dhi = Dhi + (size_t)cc * 4; dlo = Dlo + (size_t)cc * 4;
  }
  float4 f0 = *(const float4*)src;
  float4 f1 = *(const float4*)(src + 4);
  float f[8] = {f0.x, f0.y, f0.z, f0.w, f1.x, f1.y, f1.z, f1.w};
  U16 hi, lo;
  split8(f, hi, lo);
  *(uint4*)dhi = hi.u;
  *(uint4*)dlo = lo.u;
}

// ---------------- K1: RBF einsum via MFMA, j-split x4 -> f32 partials -----
// grid (16 i-tiles, 16 b, 4 jc), 512 thr (8 waves). Each block: 512 j's.
// partR layout (float4): ((((jc*16+b)*16+it)*8+wid)*2+hb)*64 + lane
__global__ __launch_bounds__(512) void k_rbf(const float* __restrict__ x,
                                             const u32* __restrict__ Whi,
                                             const u32* __restrict__ Wlo,
                                             float4* __restrict__ partR) {
  __shared__ float g_s[512];
  __shared__ u32 w_s[8192];   // 32 segs x 256 u32 (1KB each)
  const int tid = threadIdx.x;
  const int lane = tid & 63, wid = tid >> 6;
  const int it = blockIdx.x, b = blockIdx.y, jc = blockIdx.z;
  const int i0w = it * 128 + wid * 16;
  g_s[tid] = x[(size_t)b * XS + jc * 512 + tid];
  const float gi = x[(size_t)b * XS + i0w + (lane & 15)];
  f32x4 acc0 = {0.f, 0.f, 0.f, 0.f};
  f32x4 acc1 = {0.f, 0.f, 0.f, 0.f};
  const int jb = (lane >> 4) * 8;
  const int ksbase = jc * 16;

  uint4 pf[4];
  #pragma unroll
  for (int sg = 0; sg < 4; ++sg) {
    int seg = wid * 4 + sg;            // arr*16 + h*8 + ksl
    int arr = seg >> 4, h = (seg >> 3) & 1, ksl = seg & 7;
    pf[sg] = *(const uint4*)((arr ? Wlo : Whi) +
             (((size_t)h * 64 + ksbase + ksl) * 64 + lane) * 4);
  }
  for (int chunk = 0; chunk < 2; ++chunk) {
    __syncthreads();   // WAR on w_s (and covers g_s first time)
    #pragma unroll
    for (int sg = 0; sg < 4; ++sg)
      *(uint4*)&w_s[(wid * 4 + sg) * 256 + lane * 4] = pf[sg];
    if (chunk < 1) {
      #pragma unroll
      for (int sg = 0; sg < 4; ++sg) {
        int seg = wid * 4 + sg;
        int arr = seg >> 4, h = (seg >> 3) & 1, ksl = seg & 7;
        pf[sg] = *(const uint4*)((arr ? Wlo : Whi) +
                 (((size_t)h * 64 + ksbase + 8 + ksl) * 64 + lane) * 4);
      }
    }
    __syncthreads();
    #pragma unroll
    for (int ksl = 0; ksl < 8; ++ksl) {
      const float* gp = &g_s[chunk * 256 + ksl * 32 + jb];
      float4 gja = *(const float4*)gp;
      float4 gjb = *(const float4*)(gp + 4);
      float gv[8] = {gja.x, gja.y, gja.z, gja.w, gjb.x, gjb.y, gjb.z, gjb.w};
      float kv[8];
      #pragma unroll
      for (int q = 0; q < 8; ++q) {
        float d = gi - gv[q];
        kv[q] = fast_exp2(d * d * CEXP);
      }
      U16 ah, al;
      split8(kv, ah, al);
      U16 w0h, w1h, w0l, w1l;
      w0h.u = *(const uint4*)&w_s[(ksl) * 256 + lane * 4];
      w1h.u = *(const uint4*)&w_s[(8 + ksl) * 256 + lane * 4];
      w0l.u = *(const uint4*)&w_s[(16 + ksl) * 256 + lane * 4];
      w1l.u = *(const uint4*)&w_s[(24 + ksl) * 256 + lane * 4];
      acc0 = __builtin_amdgcn_mfma_f32_16x16x32_bf16(ah.v, w0h.v, acc0, 0, 0, 0);
      acc0 = __builtin_amdgcn_mfma_f32_16x16x32_bf16(al.v, w0h.v, acc0, 0, 0, 0);
      acc0 = __builtin_amdgcn_mfma_f32_16x16x32_bf16(ah.v, w0l.v, acc0, 0, 0, 0);
      acc1 = __builtin_amdgcn_mfma_f32_16x16x32_bf16(ah.v, w1h.v, acc1, 0, 0, 0);
      acc1 = __builtin_amdgcn_mfma_f32_16x16x32_bf16(al.v, w1h.v, acc1, 0, 0, 0);
      acc1 = __builtin_amdgcn_mfma_f32_16x16x32_bf16(ah.v, w1l.v, acc1, 0, 0, 0);
    }
  }
  size_t pbase = (((((size_t)jc * 16 + b) * 16 + it) * 8 + wid) * 2) * 64 + lane;
  partR[pbase]      = make_float4(acc0[0], acc0[1], acc0[2], acc0[3]);
  partR[pbase + 64] = make_float4(acc1[0], acc1[1], acc1[2], acc1[3]);
}

// ---------------- K2: reduce jc partials + bias + emb gather + bf16 pack --
__global__ __launch_bounds__(256) void k_pack(const float4* __restrict__ partR,
                                              const float* __restrict__ x,
                                              const int* __restrict__ table,
                                              const float* __restrict__ emb,
                                              const float* __restrict__ brbf,
                                              u32* __restrict__ Ahi,
                                              u32* __restrict__ Alo) {
  int u = blockIdx.x * 256 + threadIdx.x;   // 262144
  int lane = u & 63, hb = (u >> 6) & 1, wid = (u >> 7) & 7;
  int it = (u >> 10) & 15, b = u >> 14;
  float4 p0 = partR[u];
  float4 p1 = partR[262144 + u];
  float4 p2 = partR[524288 + u];
  float4 p3 = partR[786432 + u];
  int eloc = lane & 15, quad = lane >> 4;
  int e = hb * 16 + eloc;
  int i0w = it * 128 + wid * 16;
  int ib = i0w + quad * 4;
  int idx = (int)x[(size_t)b * XS + Gg + Dd];
  int4 tt = *(const int4*)&table[(size_t)idx * Gg + ib];
  float bias = brbf[e];
  float v0 = p0.x + p1.x + p2.x + p3.x + bias + emb[tt.x * 32 + e];
  float v1 = p0.y + p1.y + p2.y + p3.y + bias + emb[tt.y * 32 + e];
  float v2 = p0.z + p1.z + p2.z + p3.z + bias + emb[tt.z * 32 + e];
  float v3 = p0.w + p1.w + p2.w + p3.w + bias + emb[tt.w * 32 + e];
  int ks = i0w >> 5;
  int lp = (2 * ((i0w >> 4) & 1) + (quad >> 1)) * 16 + eloc;
  int hs = quad & 1;
  size_t off = (((size_t)(b * 2 + hb) * 64 + ks) * 64 + lp) * 4 + hs * 2;
  Ahi[off]     = pk2(v0, v1);
  Ahi[off + 1] = pk2(v2, v3);
  Alo[off]     = pk2(v0 - bftrunc(v0), v1 - bftrunc(v1));
  Alo[off + 1] = pk2(v2 - bftrunc(v2), v3 - bftrunc(v3));
}

// ---------------- K3: gene GEMM 512x1024x2048, split-bf16 MFMA ------------
// 256 blocks x 512 threads (8 waves, 2x4): BM=64 (by), BN=128 (bx), kc=4.
// Register-prefetch double buffering; partB layout [kc][n][m].
__global__ __launch_bounds__(512) void k_mm(const u32* __restrict__ Ahi,
                                            const u32* __restrict__ Alo,
                                            const u32* __restrict__ Bhi,
                                            const u32* __restrict__ Blo,
                                            float* __restrict__ part) {
  __shared__ u32 s_mm[6144];   // 24 segs x 1KB
  const int tid = threadIdx.x;
  const int lane = tid & 63, wid = tid >> 6;   // 8 waves
  const int id = blockIdx.x;
  const int pl = id & 7, by = (id >> 3) & 7, ph = id >> 6;
  const int p = ph * 8 + pl;
  const int bx = p >> 2, kc = p & 3;
  const int wm = wid >> 2, wn = wid & 3;       // 2 x 4 waves
  f32x4 acc[2][2];
  #pragma unroll
  for (int mf = 0; mf < 2; ++mf)
    #pragma unroll
    for (int nf = 0; nf < 2; ++nf) acc[mf][nf] = (f32x4){0.f, 0.f, 0.f, 0.f};

  uint4 pf[3];
  #pragma unroll
  for (int q = 0; q < 3; ++q) {
    int seg = wid * 3 + q;
    const u32* src;
    if (seg < 8) {
      int hl = seg >> 2, mf = seg & 3;
      src = (hl ? Alo : Ahi) + (((size_t)(by * 4 + mf) * 64 + kc * 16) * 64 + lane) * 4;
    } else {
      int t = seg - 8, hl = t >> 3, nf = t & 7;
      src = (hl ? Blo : Bhi) + (((size_t)(bx * 8 + nf) * 64 + kc * 16) * 64 + lane) * 4;
    }
    pf[q] = *(const uint4*)src;
  }
  for (int stage = 0; stage < 16; ++stage) {
    __syncthreads();
    #pragma unroll
    for (int q = 0; q < 3; ++q)
      *(uint4*)&s_mm[(wid * 3 + q) * 256 + lane * 4] = pf[q];
    if (stage < 15) {
      const int ks = kc * 16 + stage + 1;
      #pragma unroll
      for (int q = 0; q < 3; ++q) {
        int seg = wid * 3 + q;
        const u32* src;
        if (seg < 8) {
          int hl = seg >> 2, mf = seg & 3;
          src = (hl ? Alo : Ahi) + (((size_t)(by * 4 + mf) * 64 + ks) * 64 + lane) * 4;
        } else {
          int t = seg - 8, hl = t >> 3, nf = t & 7;
          src = (hl ? Blo : Bhi) + (((size_t)(bx * 8 + nf) * 64 + ks) * 64 + lane) * 4;
        }
        pf[q] = *(const uint4*)src;
      }
    }
    __syncthreads();
    U16 ah[2], al[2], bh[2], bl[2];
    #pragma unroll
    for (int mf = 0; mf < 2; ++mf) {
      ah[mf].u = *(const uint4*)&s_mm[(0 + wm * 2 + mf) * 256 + lane * 4];
      al[mf].u = *(const uint4*)&s_mm[(4 + wm * 2 + mf) * 256 + lane * 4];
    }
    #pragma unroll
    for (int nf = 0; nf < 2; ++nf) {
      bh[nf].u = *(const uint4*)&s_mm[(8 + wn * 2 + nf) * 256 + lane * 4];
      bl[nf].u = *(const uint4*)&s_mm[(16 + wn * 2 + nf) * 256 + lane * 4];
    }
    #pragma unroll
    for (int mf = 0; mf < 2; ++mf) {
      #pragma unroll
      for (int nf = 0; nf < 2; ++nf) {
        acc[mf][nf] = __builtin_amdgcn_mfma_f32_16x16x32_bf16(ah[mf].v, bh[nf].v, acc[mf][nf], 0, 0, 0);
        acc[mf][nf] = __builtin_amdgcn_mfma_f32_16x16x32_bf16(al[mf].v, bh[nf].v, acc[mf][nf], 0, 0, 0);
        acc[mf][nf] = __builtin_amdgcn_mfma_f32_16x16x32_bf16(ah[mf].v, bl[nf].v, acc[mf][nf], 0, 0, 0);
      }
    }
  }
  const int quad = lane >> 4, nl = lane & 15;
  #pragma unroll
  for (int mf = 0; mf < 2; ++mf) {
    #pragma unroll
    for (int nf = 0; nf < 2; ++nf) {
      int n  = bx * 128 + wn * 32 + nf * 16 + nl;
      int m0 = by * 64 + wm * 32 + mf * 16 + quad * 4;
      float4 st = make_float4(acc[mf][nf][0], acc[mf][nf][1], acc[mf][nf][2], acc[mf][nf][3]);
      *(float4*)&part[(size_t)kc * 524288 + (size_t)n * 512 + m0] = st;
    }
  }
}

// ---------------- batchnorm over 512 threads, 6 channels -----------------
__device__ inline void bn512(float* v, int wv, int lane,
                             float (*r1)[6], float (*r2)[6]) {
  float s[6], q[6];
  #pragma unroll
  for (int c = 0; c < 6; ++c) {
    float a = v[c];
    s[c] = wred(a);
    q[c] = wred(a * a);
  }
  __syncthreads();
  if (lane == 0) {
    #pragma unroll
    for (int c = 0; c < 6; ++c) { r1[wv][c] = s[c]; r2[wv][c] = q[c]; }
  }
  __syncthreads();
  #pragma unroll
  for (int c = 0; c < 6; ++c) {
    float S = 0.f, Q = 0.f;
    #pragma unroll
    for (int w = 0; w < 8; ++w) { S += r1[w][c]; Q += r2[w][c]; }
    float m  = S * (1.0f / 512.0f);
    float va = Q * (1.0f / 512.0f) - m * m;
    v[c] = (v[c] - m) * rsqrtf(va + EPSf);
  }
}

// ---------------- K4: leaf term; reads partB directly (fused reduce+bias) -
__global__ __launch_bounds__(512) void k_leaf(const float* __restrict__ part,
                                              const float* __restrict__ bdg,
                                              const float* __restrict__ W1,
                                              const float* __restrict__ b1,
                                              const float* __restrict__ Wc,
                                              const float* __restrict__ bc,
                                              float* __restrict__ outp) {
  const int l = blockIdx.x, tid = threadIdx.x;   // tid = b*32+e
  const int wv = tid >> 6, lane = tid & 63;
  __shared__ float r1[8][6], r2[8][6];
  float cv[64];
  #pragma unroll
  for (int i = 0; i < 64; ++i) {
    int n = l * 64 + i;
    const float* pp = part + (size_t)n * 512 + tid;
    cv[i] = pp[0] + pp[524288] + pp[2 * 524288] + pp[3 * 524288] + bdg[n];
  }
  const float* w1 = W1 + l * 6 * 64;
  float h[6];
  #pragma unroll
  for (int hh = 0; hh < 6; ++hh) {
    float s = b1[l * 6 + hh];
    #pragma unroll
    for (int i = 0; i < 64; ++i) s = fmaf(cv[i], w1[hh * 64 + i], s);
    h[hh] = s;
  }
  bn512(h, wv, lane, r1, r2);
  float c[6];
  #pragma unroll
  for (int k = 0; k < 6; ++k) {
    float s = bc[l * 6 + k];
    #pragma unroll
    for (int hh = 0; hh < 6; ++hh) s = fmaf(h[hh], Wc[l * 36 + k * 6 + hh], s);
    c[k] = s;
  }
  bn512(c, wv, lane, r1, r2);
  float* o = outp + (((size_t)(l >> 2) * 512 + tid) * 24 + (l & 3) * 6);
  #pragma unroll
  for (int k = 0; k < 6; ++k) o[k] = c[k];
}

// ---------------- K5: mid term --------------------------------------------
__global__ __launch_bounds__(512) void k_mid(const float* __restrict__ gin,
                                             const float* __restrict__ W1,
                                             const float* __restrict__ b1,
                                             const float* __restrict__ Wc,
                                             const float* __restrict__ bc,
                                             float* __restrict__ outp) {
  const int l = blockIdx.x, tid = threadIdx.x;
  const int wv = tid >> 6, lane = tid & 63;
  __shared__ float r1[8][6], r2[8][6];
  const float* ci = gin + ((size_t)l * 512 + tid) * 24;
  float cv[24];
  #pragma unroll
  for (int q = 0; q < 6; ++q) *(float4*)&cv[q * 4] = ((const float4*)ci)[q];
  const float* w1 = W1 + l * 6 * 24;
  float h[6];
  #pragma unroll
  for (int hh = 0; hh < 6; ++hh) {
    float s = b1[l * 6 + hh];
    #pragma unroll
    for (int i = 0; i < 24; ++i) s = fmaf(cv[i], w1[hh * 24 + i], s);
    h[hh] = s;
  }
  bn512(h, wv, lane, r1, r2);
  float c[6];
  #pragma unroll
  for (int k = 0; k < 6; ++k) {
    float s = bc[l * 6 + k];
    #pragma unroll
    for (int hh = 0; hh < 6; ++hh) s = fmaf(h[hh], Wc[l * 36 + k * 6 + hh], s);
    c[k] = s;
  }
  bn512(c, wv, lane, r1, r2);
  float* o = outp + ((size_t)tid * 24 + l * 6);
  #pragma unroll
  for (int k = 0; k < 6; ++k) o[k] = c[k];
}

// ---------------- K6: drug layer 1 — block per column, wave per batch -----
__global__ __launch_bounds__(1024) void k_drug1(const float* __restrict__ x,
                                                const float* __restrict__ Wd1,
                                                const float* __restrict__ bd1,
                                                float* __restrict__ d1) {
  const int c = blockIdx.x;        // 0..99
  const int tid = threadIdx.x;
  const int b = tid >> 6, lane = tid & 63;
  const float* xb = x + (size_t)b * XS + Gg;
  const float* w = Wd1 + (size_t)c * 2048;
  float s = 0.f;
  #pragma unroll
  for (int q = 0; q < 8; ++q) {
    int k = q * 256 + lane * 4;
    float4 xv = *(const float4*)(xb + k);
    float4 wv = *(const float4*)(w + k);
    s = fmaf(xv.x, wv.x, s);
    s = fmaf(xv.y, wv.y, s);
    s = fmaf(xv.z, wv.z, s);
    s = fmaf(xv.w, wv.w, s);
  }
  s = wred(s);
  __shared__ float y[16];
  if (lane == 0) y[b] = tanhf(s + bd1[c]);
  __syncthreads();
  if (tid < 16) {
    float S = 0.f, Q = 0.f;
    #pragma unroll
    for (int bb = 0; bb < 16; ++bb) { float v = y[bb]; S += v; Q += v * v; }
    float m = S * (1.0f / 16.0f), va = Q * (1.0f / 16.0f) - m * m;
    d1[tid * 100 + c] = (y[tid] - m) * rsqrtf(va + EPSf);
  }
}

// ---------------- K7: fused root term + drug layers 2-3 + final head ------
__global__ __launch_bounds__(512) void k_rootfinal(const float* __restrict__ rootin,
                                                   const float* __restrict__ d1,
                                                   const float* __restrict__ Wr1,
                                                   const float* __restrict__ br1,
                                                   const float* __restrict__ Wrc,
                                                   const float* __restrict__ brc,
                                                   const float* __restrict__ Wrd,
                                                   const float* __restrict__ brd,
                                                   const float* __restrict__ Wd2,
                                                   const float* __restrict__ bd2,
                                                   const float* __restrict__ Wd3,
                                                   const float* __restrict__ bd3,
                                                   const float* __restrict__ Wf,
                                                   const float* __restrict__ bf,
                                                   const float* __restrict__ Wfa,
                                                   const float* __restrict__ bfa,
                                                   const float* __restrict__ Wfo,
                                                   const float* __restrict__ bfo,
                                                   float* __restrict__ out) {
  const int tid = threadIdx.x;
  const int wv = tid >> 6, lane = tid & 63;
  __shared__ float r1[8][6], r2[8][6];
  __shared__ float w2s[50 * 101];
  __shared__ float d1s[1600];
  __shared__ float r2ds[96];
  // issue the big staging loads first; root compute hides their latency
  for (int u = tid; u < 5000; u += 512) w2s[(u / 100) * 101 + (u % 100)] = Wd2[u];
  for (int u = tid; u < 1600; u += 512) d1s[u] = d1[u];

  // ---- root term ----
  const float* ci = rootin + (size_t)tid * 24;
  float cv[24];
  #pragma unroll
  for (int q = 0; q < 6; ++q) *(float4*)&cv[q * 4] = ((const float4*)ci)[q];
  float h[6];
  #pragma unroll
  for (int hh = 0; hh < 6; ++hh) {
    float s = br1[hh];
    #pragma unroll
    for (int i = 0; i < 24; ++i) s = fmaf(cv[i], Wr1[hh * 24 + i], s);
    h[hh] = s;
  }
  bn512(h, wv, lane, r1, r2);
  float c[6];
  #pragma unroll
  for (int k = 0; k < 6; ++k) {
    float s = brc[k];
    #pragma unroll
    for (int hh = 0; hh < 6; ++hh) s = fmaf(h[hh], Wrc[k * 6 + hh], s);
    c[k] = s;
  }
  bn512(c, wv, lane, r1, r2);
  float mv = (c[0] + c[1] + c[2] + c[3] + c[4] + c[5]) * (1.0f / 6.0f);
  __shared__ float shm[512];
  shm[tid] = mv;
  __syncthreads();
  __shared__ float st[96];
  if (tid < 96) {
    int b = tid / 6, hh = tid % 6;
    float s = brd[hh];
    #pragma unroll
    for (int e = 0; e < 32; ++e) s = fmaf(shm[b * 32 + e], Wrd[hh * 32 + e], s);
    st[tid] = tanhf(s);
  }
  __syncthreads();
  if (tid < 6) {
    float S = 0.f, Q = 0.f;
    for (int b = 0; b < 16; ++b) { float v = st[b * 6 + tid]; S += v; Q += v * v; }
    float m = S * (1.0f / 16.0f), va = Q * (1.0f / 16.0f) - m * m;
    float iv = rsqrtf(va + EPSf);
    for (int b = 0; b < 16; ++b) r2ds[b * 6 + tid] = (st[b * 6 + tid] - m) * iv;
  }
  __syncthreads();

  // ---- drug layers 2-3 + final head ----
  __shared__ float s2[800], mu2[50], iv2[50];
  for (int u = tid; u < 800; u += 512) {
    int b = u / 50, cc = u % 50;
    float s = bd2[cc];
    #pragma unroll
    for (int k = 0; k < 100; ++k) s = fmaf(d1s[b * 100 + k], w2s[cc * 101 + k], s);
    s2[u] = tanhf(s);
  }
  __syncthreads();
  if (tid < 50) {
    float S = 0.f, Q = 0.f;
    #pragma unroll
    for (int b = 0; b < 16; ++b) { float v = s2[b * 50 + tid]; S += v; Q += v * v; }
    float m = S * (1.0f / 16.0f), va = Q * (1.0f / 16.0f) - m * m;
    mu2[tid] = m; iv2[tid] = rsqrtf(va + EPSf);
  }
  __syncthreads();
  __shared__ float s3[96], mu3[6], iv3[6];
  if (tid < 96) {
    int b = tid / 6, cc = tid % 6;
    float s = bd3[cc];
    #pragma unroll
    for (int k = 0; k < 50; ++k)
      s = fmaf((s2[b * 50 + k] - mu2[k]) * iv2[k], Wd3[cc * 50 + k], s);
    s3[tid] = tanhf(s);
  }
  __syncthreads();
  if (tid < 6) {
    float S = 0.f, Q = 0.f;
    #pragma unroll
    for (int b = 0; b < 16; ++b) { float v = s3[b * 6 + tid]; S += v; Q += v * v; }
    float m = S * (1.0f / 16.0f), va = Q * (1.0f / 16.0f) - m * m;
    mu3[tid] = m; iv3[tid] = rsqrtf(va + EPSf);
  }
  __syncthreads();
  __shared__ float sf[96], muf[6], ivf[6];
  if (tid < 96) {
    int b = tid / 6, cc = tid % 6;
    float s = bf[cc];
    #pragma unroll
    for (int q = 0; q < 6; ++q) s = fmaf(r2ds[b * 6 + q], Wf[cc * 12 + q], s);
    #pragma unroll
    for (int q = 0; q < 6; ++q)
      s = fmaf((s3[b * 6 + q] - mu3[q]) * iv3[q], Wf[cc * 12 + 6 + q], s);
    sf[tid] = tanhf(s);
  }
  __syncthreads();
  if (tid < 6) {
    float S = 0.f, Q = 0.f;
    #pragma unroll
    for (int b = 0; b < 16; ++b) { float v = sf[b * 6 + tid]; S += v; Q += v * v; }
    float m = S * (1.0f / 16.0f), va = Q * (1.0f / 16.0f) - m * m;
    muf[tid] = m; ivf[tid] = rsqrtf(va + EPSf);
  }
  __syncthreads();
  if (tid < 16) {
    float s = bfa[0];
    #pragma unroll
    for (int q = 0; q < 6; ++q)
      s = fmaf((sf[tid * 6 + q] - muf[q]) * ivf[q], Wfa[q], s);
    float a = tanhf(s);
    out[tid] = a * Wfo[0] + bfo[0];
  }
}

extern "C" void kernel_launch(void* const* d_in, const int* in_sizes, int n_in,
                              void* d_out, int out_size, void* d_ws, size_t ws_size,
                              hipStream_t stream) {
  const float* x     = (const float*)d_in[0];
  const int*   table = (const int*)d_in[1];
  const float* Wrbf  = (const float*)d_in[2];
  const float* brbf  = (const float*)d_in[3];
  const float* emb   = (const float*)d_in[4];
  const float* Wdg   = (const float*)d_in[5];
  const float* bdg   = (const float*)d_in[6];
  const float* Wl1   = (const float*)d_in[7];
  const float* bl1   = (const float*)d_in[8];
  const float* Wlc   = (const float*)d_in[9];
  const float* blc   = (const float*)d_in[10];
  const float* Wm1   = (const float*)d_in[13];
  const float* bm1   = (const float*)d_in[14];
  const float* Wmc   = (const float*)d_in[15];
  const float* bmc   = (const float*)d_in[16];
  const float* Wr1   = (const float*)d_in[19];
  const float* br1   = (const float*)d_in[20];
  const float* Wrc   = (const float*)d_in[21];
  const float* brc   = (const float*)d_in[22];
  const float* Wrd   = (const float*)d_in[23];
  const float* brd   = (const float*)d_in[24];
  const float* Wd1   = (const float*)d_in[25];
  const float* bd1   = (const float*)d_in[26];
  const float* Wd2   = (const float*)d_in[27];
  const float* bd2   = (const float*)d_in[28];
  const float* Wd3   = (const float*)d_in[29];
  const float* bd3   = (const float*)d_in[30];
  const float* Wf    = (const float*)d_in[31];
  const float* bf    = (const float*)d_in[32];
  const float* Wfa   = (const float*)d_in[33];
  const float* bfa   = (const float*)d_in[34];
  const float* Wfo   = (const float*)d_in[35];
  const float* bfo   = (const float*)d_in[36];
  float* out = (float*)d_out;

  u32* Rhi = (u32*)d_ws;                   // 32768
  u32* Rlo = Rhi + 32768;                  // 32768
  u32* Dhi = Rlo + 32768;                  // 1048576
  u32* Dlo = Dhi + 1048576;                // 1048576
  u32* Ahi = Dlo + 1048576;                // 524288
  u32* Alo = Ahi + 524288;                 // 524288
  float4* partR = (float4*)(Alo + 524288); // 1048576 float4 (16MB)
  float* partB = (float*)(partR + 1048576);// 4 * 524288
  float* midin = partB + 4 * 524288;       // 49152
  float* rootin= midin + 49152;            // 12288
  float* d1    = rootin + 12288;           // 1600

  hipLaunchKernelGGL(k_drug1,     dim3(100),       dim3(1024), 0, stream, x, Wd1, bd1, d1);
  hipLaunchKernelGGL(k_split,     dim3(1056),      dim3(256),  0, stream, Wrbf, Wdg, Rhi, Rlo, Dhi, Dlo);
  hipLaunchKernelGGL(k_rbf,       dim3(16, 16, 4), dim3(512),  0, stream, x, Rhi, Rlo, partR);
  hipLaunchKernelGGL(k_pack,      dim3(1024),      dim3(256),  0, stream, partR, x, table, emb, brbf, Ahi, Alo);
  hipLaunchKernelGGL(k_mm,        dim3(256),       dim3(512),  0, stream, Ahi, Alo, Dhi, Dlo, partB);
  hipLaunchKernelGGL(k_leaf,      dim3(16),        dim3(512),  0, stream, partB, bdg, Wl1, bl1, Wlc, blc, midin);
  hipLaunchKernelGGL(k_mid,       dim3(4),         dim3(512),  0, stream, midin, Wm1, bm1, Wmc, bmc, rootin);
  hipLaunchKernelGGL(k_rootfinal, dim3(1),         dim3(512),  0, stream, rootin, d1,
                     Wr1, br1, Wrc, brc, Wrd, brd, Wd2, bd2, Wd3, bd3,
                     Wf, bf, Wfa, bfa, Wfo, bfo, out);
}

// Round 9
// 115.568 us; speedup vs baseline: 1.0931x; 1.0931x over previous
//
#include <hip/hip_runtime.h>
#include <hip/hip_bf16.h>

// Sizes
#define Bb 16
#define Gg 2048
#define Dd 2048
#define XS 4097   // G + D + 1
#define EPSf 1e-5f
#define CEXP (-0.72134752044448170368f)   // -gamma * log2(e), gamma = 0.5

typedef unsigned int u32;
typedef __attribute__((ext_vector_type(8))) short bf16x8;
typedef __attribute__((ext_vector_type(4))) float f32x4;

union U16 { uint4 u; bf16x8 v; };

__device__ inline float fast_exp2(float x) {
#if __has_builtin(__builtin_amdgcn_exp2f)
  return __builtin_amdgcn_exp2f(x);
#else
  return exp2f(x);
#endif
}

// pack two f32 into one u32 of 2 bf16 (truncation): low half from a, high from b
__device__ inline u32 pk2(float a, float b) {
  return __builtin_amdgcn_perm(__float_as_uint(b), __float_as_uint(a), 0x07060302u);
}
__device__ inline float bftrunc(float a) {
  return __uint_as_float(__float_as_uint(a) & 0xFFFF0000u);
}

// split 8 floats into hi/lo bf16x8 fragments
__device__ inline void split8(const float* f, U16& hi, U16& lo) {
  u32 h[4], l[4];
  #pragma unroll
  for (int p = 0; p < 4; ++p) {
    float a = f[2 * p], b = f[2 * p + 1];
    h[p] = pk2(a, b);
    l[p] = pk2(a - bftrunc(a), b - bftrunc(b));
  }
  hi.u = make_uint4(h[0], h[1], h[2], h[3]);
  lo.u = make_uint4(l[0], l[1], l[2], l[3]);
}

__device__ inline float wred(float v) {
  #pragma unroll
  for (int o = 32; o > 0; o >>= 1) v += __shfl_xor(v, o, 64);
  return v;
}

// ---------------- K0: split weights into MFMA-frag-linear bf16 hi/lo ------
__global__ __launch_bounds__(256) void k_split(const float* __restrict__ Wrbf,
                                               const float* __restrict__ Wdg,
                                               u32* __restrict__ Rhi, u32* __restrict__ Rlo,
                                               u32* __restrict__ Dhi, u32* __restrict__ Dlo) {
  int c = blockIdx.x * 256 + threadIdx.x;   // 270336 total
  const float* src;
  u32 *dhi, *dlo;
  if (c < 8192) {
    int h = c >> 12, ks = (c >> 6) & 63, l = c & 63;
    src = Wrbf + (h * 16 + (l & 15)) * Gg + ks * 32 + (l >> 4) * 8;
    dhi = Rhi + (size_t)c * 4; dlo = Rlo + (size_t)c * 4;
  } else {
    int cc = c - 8192;
    int nf = cc >> 12, ks = (cc >> 6) & 63, l = cc & 63;
    src = Wdg + (size_t)(nf * 16 + (l & 15)) * Gg + ks * 32 + (l >> 4) * 8;
    dhi = Dhi + (size_t)cc * 4; dlo = Dlo + (size_t)cc * 4;
  }
  float4 f0 = *(const float4*)src;
  float4 f1 = *(const float4*)(src + 4);
  float f[8] = {f0.x, f0.y, f0.z, f0.w, f1.x, f1.y, f1.z, f1.w};
  U16 hi, lo;
  split8(f, hi, lo);
  *(uint4*)dhi = hi.u;
  *(uint4*)dlo = lo.u;
}

// ---------------- K1: fused RBF einsum + pack -----------------------------
// grid (32 i-tiles of 64, 16 b), 1024 thr = 16 waves.
// wave w: isub = w>>2 (16 i-rows), jcw = w&3 (512-j chunk).
// Weight fragments read straight from global (L2-resident, no LDS staging,
// no barriers in main loop). jc-partials reduced via LDS; pack epilogue
// (bias + emb gather + split-bf16 frag-linear write) fused.
__global__ __launch_bounds__(1024) void k_rbf2(const float* __restrict__ x,
                                               const u32* __restrict__ Whi,
                                               const u32* __restrict__ Wlo,
                                               const int* __restrict__ table,
                                               const float* __restrict__ emb,
                                               const float* __restrict__ brbf,
                                               u32* __restrict__ Ahi,
                                               u32* __restrict__ Alo) {
  __shared__ float g_s[2048];
  __shared__ float red[16][64][8];
  const int tid = threadIdx.x;
  const int lane = tid & 63, wid = tid >> 6;
  const int isub = wid >> 2, jcw = wid & 3;
  const int i0 = blockIdx.x * 64, b = blockIdx.y;
  const int i0w = i0 + isub * 16;
  g_s[tid] = x[(size_t)b * XS + tid];
  g_s[tid + 1024] = x[(size_t)b * XS + 1024 + tid];
  const float gi = x[(size_t)b * XS + i0w + (lane & 15)];
  f32x4 acc0 = {0.f, 0.f, 0.f, 0.f};
  f32x4 acc1 = {0.f, 0.f, 0.f, 0.f};
  const int jb = (lane >> 4) * 8;
  __syncthreads();   // g_s ready

  #pragma unroll
  for (int ksl = 0; ksl < 16; ++ksl) {
    const int ks = jcw * 16 + ksl;
    const float* gp = &g_s[ks * 32 + jb];
    float4 gja = *(const float4*)gp;
    float4 gjb = *(const float4*)(gp + 4);
    float gv[8] = {gja.x, gja.y, gja.z, gja.w, gjb.x, gjb.y, gjb.z, gjb.w};
    float kv[8];
    #pragma unroll
    for (int q = 0; q < 8; ++q) {
      float d = gi - gv[q];
      kv[q] = fast_exp2(d * d * CEXP);
    }
    U16 ah, al;
    split8(kv, ah, al);
    U16 w0h, w1h, w0l, w1l;
    const size_t wo = (size_t)ks * 256 + lane * 4;
    w0h.u = *(const uint4*)(Whi + wo);
    w1h.u = *(const uint4*)(Whi + 16384 + wo);
    w0l.u = *(const uint4*)(Wlo + wo);
    w1l.u = *(const uint4*)(Wlo + 16384 + wo);
    acc0 = __builtin_amdgcn_mfma_f32_16x16x32_bf16(ah.v, w0h.v, acc0, 0, 0, 0);
    acc0 = __builtin_amdgcn_mfma_f32_16x16x32_bf16(al.v, w0h.v, acc0, 0, 0, 0);
    acc0 = __builtin_amdgcn_mfma_f32_16x16x32_bf16(ah.v, w0l.v, acc0, 0, 0, 0);
    acc1 = __builtin_amdgcn_mfma_f32_16x16x32_bf16(ah.v, w1h.v, acc1, 0, 0, 0);
    acc1 = __builtin_amdgcn_mfma_f32_16x16x32_bf16(al.v, w1h.v, acc1, 0, 0, 0);
    acc1 = __builtin_amdgcn_mfma_f32_16x16x32_bf16(ah.v, w1l.v, acc1, 0, 0, 0);
  }
  #pragma unroll
  for (int k = 0; k < 4; ++k) { red[wid][lane][k] = acc0[k]; red[wid][lane][4 + k] = acc1[k]; }
  __syncthreads();
  if (jcw == 0) {
    float f[8];
    #pragma unroll
    for (int k = 0; k < 8; ++k)
      f[k] = red[isub * 4][lane][k] + red[isub * 4 + 1][lane][k] +
             red[isub * 4 + 2][lane][k] + red[isub * 4 + 3][lane][k];
    const int idx = (int)x[(size_t)b * XS + Gg + Dd];
    const int eloc = lane & 15, quad = lane >> 4;
    const int ib = i0w + quad * 4;
    int4 tt = *(const int4*)&table[(size_t)idx * Gg + ib];
    const int ks = i0w >> 5;
    const int lp = (2 * ((i0w >> 4) & 1) + (quad >> 1)) * 16 + eloc;
    const int hs = quad & 1;
    #pragma unroll
    for (int hb = 0; hb < 2; ++hb) {
      const int e = hb * 16 + eloc;
      const float bias = brbf[e];
      float v0 = f[hb * 4 + 0] + bias + emb[tt.x * 32 + e];
      float v1 = f[hb * 4 + 1] + bias + emb[tt.y * 32 + e];
      float v2 = f[hb * 4 + 2] + bias + emb[tt.z * 32 + e];
      float v3 = f[hb * 4 + 3] + bias + emb[tt.w * 32 + e];
      size_t off = (((size_t)(b * 2 + hb) * 64 + ks) * 64 + lp) * 4 + hs * 2;
      Ahi[off]     = pk2(v0, v1);
      Ahi[off + 1] = pk2(v2, v3);
      Alo[off]     = pk2(v0 - bftrunc(v0), v1 - bftrunc(v1));
      Alo[off + 1] = pk2(v2 - bftrunc(v2), v3 - bftrunc(v3));
    }
  }
}

// ---------------- K2: gene GEMM 512x1024x2048, split-bf16 MFMA ------------
// 256 blocks x 512 threads (8 waves, 2x4): BM=64 (by), BN=128 (bx), kc=4.
// (R7-verified version.) partB layout [kc][n][m].
__global__ __launch_bounds__(512) void k_mm(const u32* __restrict__ Ahi,
                                            const u32* __restrict__ Alo,
                                            const u32* __restrict__ Bhi,
                                            const u32* __restrict__ Blo,
                                            float* __restrict__ part) {
  __shared__ u32 s_mm[6144];   // 24 segs x 1KB
  const int tid = threadIdx.x;
  const int lane = tid & 63, wid = tid >> 6;   // 8 waves
  const int id = blockIdx.x;
  const int pl = id & 7, by = (id >> 3) & 7, ph = id >> 6;
  const int p = ph * 8 + pl;
  const int bx = p >> 2, kc = p & 3;
  const int wm = wid >> 2, wn = wid & 3;       // 2 x 4 waves
  f32x4 acc[2][2];
  #pragma unroll
  for (int mf = 0; mf < 2; ++mf)
    #pragma unroll
    for (int nf = 0; nf < 2; ++nf) acc[mf][nf] = (f32x4){0.f, 0.f, 0.f, 0.f};

  uint4 pf[3];
  #pragma unroll
  for (int q = 0; q < 3; ++q) {
    int seg = wid * 3 + q;
    const u32* src;
    if (seg < 8) {
      int hl = seg >> 2, mf = seg & 3;
      src = (hl ? Alo : Ahi) + (((size_t)(by * 4 + mf) * 64 + kc * 16) * 64 + lane) * 4;
    } else {
      int t = seg - 8, hl = t >> 3, nf = t & 7;
      src = (hl ? Blo : Bhi) + (((size_t)(bx * 8 + nf) * 64 + kc * 16) * 64 + lane) * 4;
    }
    pf[q] = *(const uint4*)src;
  }
  for (int stage = 0; stage < 16; ++stage) {
    __syncthreads();
    #pragma unroll
    for (int q = 0; q < 3; ++q)
      *(uint4*)&s_mm[(wid * 3 + q) * 256 + lane * 4] = pf[q];
    if (stage < 15) {
      const int ks = kc * 16 + stage + 1;
      #pragma unroll
      for (int q = 0; q < 3; ++q) {
        int seg = wid * 3 + q;
        const u32* src;
        if (seg < 8) {
          int hl = seg >> 2, mf = seg & 3;
          src = (hl ? Alo : Ahi) + (((size_t)(by * 4 + mf) * 64 + ks) * 64 + lane) * 4;
        } else {
          int t = seg - 8, hl = t >> 3, nf = t & 7;
          src = (hl ? Blo : Bhi) + (((size_t)(bx * 8 + nf) * 64 + ks) * 64 + lane) * 4;
        }
        pf[q] = *(const uint4*)src;
      }
    }
    __syncthreads();
    U16 ah[2], al[2], bh[2], bl[2];
    #pragma unroll
    for (int mf = 0; mf < 2; ++mf) {
      ah[mf].u = *(const uint4*)&s_mm[(0 + wm * 2 + mf) * 256 + lane * 4];
      al[mf].u = *(const uint4*)&s_mm[(4 + wm * 2 + mf) * 256 + lane * 4];
    }
    #pragma unroll
    for (int nf = 0; nf < 2; ++nf) {
      bh[nf].u = *(const uint4*)&s_mm[(8 + wn * 2 + nf) * 256 + lane * 4];
      bl[nf].u = *(const uint4*)&s_mm[(16 + wn * 2 + nf) * 256 + lane * 4];
    }
    #pragma unroll
    for (int mf = 0; mf < 2; ++mf) {
      #pragma unroll
      for (int nf = 0; nf < 2; ++nf) {
        acc[mf][nf] = __builtin_amdgcn_mfma_f32_16x16x32_bf16(ah[mf].v, bh[nf].v, acc[mf][nf], 0, 0, 0);
        acc[mf][nf] = __builtin_amdgcn_mfma_f32_16x16x32_bf16(al[mf].v, bh[nf].v, acc[mf][nf], 0, 0, 0);
        acc[mf][nf] = __builtin_amdgcn_mfma_f32_16x16x32_bf16(ah[mf].v, bl[nf].v, acc[mf][nf], 0, 0, 0);
      }
    }
  }
  const int quad = lane >> 4, nl = lane & 15;
  #pragma unroll
  for (int mf = 0; mf < 2; ++mf) {
    #pragma unroll
    for (int nf = 0; nf < 2; ++nf) {
      int n  = bx * 128 + wn * 32 + nf * 16 + nl;
      int m0 = by * 64 + wm * 32 + mf * 16 + quad * 4;
      float4 st = make_float4(acc[mf][nf][0], acc[mf][nf][1], acc[mf][nf][2], acc[mf][nf][3]);
      *(float4*)&part[(size_t)kc * 524288 + (size_t)n * 512 + m0] = st;
    }
  }
}

// ---------------- batchnorm over 512 threads, 6 channels -----------------
__device__ inline void bn512(float* v, int wv, int lane,
                             float (*r1)[6], float (*r2)[6]) {
  float s[6], q[6];
  #pragma unroll
  for (int c = 0; c < 6; ++c) {
    float a = v[c];
    s[c] = wred(a);
    q[c] = wred(a * a);
  }
  __syncthreads();
  if (lane == 0) {
    #pragma unroll
    for (int c = 0; c < 6; ++c) { r1[wv][c] = s[c]; r2[wv][c] = q[c]; }
  }
  __syncthreads();
  #pragma unroll
  for (int c = 0; c < 6; ++c) {
    float S = 0.f, Q = 0.f;
    #pragma unroll
    for (int w = 0; w < 8; ++w) { S += r1[w][c]; Q += r2[w][c]; }
    float m  = S * (1.0f / 512.0f);
    float va = Q * (1.0f / 512.0f) - m * m;
    v[c] = (v[c] - m) * rsqrtf(va + EPSf);
  }
}

// ---------------- K3: leaf term; reads partB directly (fused reduce+bias) -
__global__ __launch_bounds__(512) void k_leaf(const float* __restrict__ part,
                                              const float* __restrict__ bdg,
                                              const float* __restrict__ W1,
                                              const float* __restrict__ b1,
                                              const float* __restrict__ Wc,
                                              const float* __restrict__ bc,
                                              float* __restrict__ outp) {
  const int l = blockIdx.x, tid = threadIdx.x;   // tid = b*32+e
  const int wv = tid >> 6, lane = tid & 63;
  __shared__ float r1[8][6], r2[8][6];
  float cv[64];
  #pragma unroll
  for (int i = 0; i < 64; ++i) {
    int n = l * 64 + i;
    const float* pp = part + (size_t)n * 512 + tid;
    cv[i] = pp[0] + pp[524288] + pp[2 * 524288] + pp[3 * 524288] + bdg[n];
  }
  const float* w1 = W1 + l * 6 * 64;
  float h[6];
  #pragma unroll
  for (int hh = 0; hh < 6; ++hh) {
    float s = b1[l * 6 + hh];
    #pragma unroll
    for (int i = 0; i < 64; ++i) s = fmaf(cv[i], w1[hh * 64 + i], s);
    h[hh] = s;
  }
  bn512(h, wv, lane, r1, r2);
  float c[6];
  #pragma unroll
  for (int k = 0; k < 6; ++k) {
    float s = bc[l * 6 + k];
    #pragma unroll
    for (int hh = 0; hh < 6; ++hh) s = fmaf(h[hh], Wc[l * 36 + k * 6 + hh], s);
    c[k] = s;
  }
  bn512(c, wv, lane, r1, r2);
  float* o = outp + (((size_t)(l >> 2) * 512 + tid) * 24 + (l & 3) * 6);
  #pragma unroll
  for (int k = 0; k < 6; ++k) o[k] = c[k];
}

// ---------------- K4: mid term --------------------------------------------
__global__ __launch_bounds__(512) void k_mid(const float* __restrict__ gin,
                                             const float* __restrict__ W1,
                                             const float* __restrict__ b1,
                                             const float* __restrict__ Wc,
                                             const float* __restrict__ bc,
                                             float* __restrict__ outp) {
  const int l = blockIdx.x, tid = threadIdx.x;
  const int wv = tid >> 6, lane = tid & 63;
  __shared__ float r1[8][6], r2[8][6];
  const float* ci = gin + ((size_t)l * 512 + tid) * 24;
  float cv[24];
  #pragma unroll
  for (int q = 0; q < 6; ++q) *(float4*)&cv[q * 4] = ((const float4*)ci)[q];
  const float* w1 = W1 + l * 6 * 24;
  float h[6];
  #pragma unroll
  for (int hh = 0; hh < 6; ++hh) {
    float s = b1[l * 6 + hh];
    #pragma unroll
    for (int i = 0; i < 24; ++i) s = fmaf(cv[i], w1[hh * 24 + i], s);
    h[hh] = s;
  }
  bn512(h, wv, lane, r1, r2);
  float c[6];
  #pragma unroll
  for (int k = 0; k < 6; ++k) {
    float s = bc[l * 6 + k];
    #pragma unroll
    for (int hh = 0; hh < 6; ++hh) s = fmaf(h[hh], Wc[l * 36 + k * 6 + hh], s);
    c[k] = s;
  }
  bn512(c, wv, lane, r1, r2);
  float* o = outp + ((size_t)tid * 24 + l * 6);
  #pragma unroll
  for (int k = 0; k < 6; ++k) o[k] = c[k];
}

// ---------------- K5: drug layer 1 — block per column, wave per batch -----
__global__ __launch_bounds__(1024) void k_drug1(const float* __restrict__ x,
                                                const float* __restrict__ Wd1,
                                                const float* __restrict__ bd1,
                                                float* __restrict__ d1) {
  const int c = blockIdx.x;        // 0..99
  const int tid = threadIdx.x;
  const int b = tid >> 6, lane = tid & 63;
  const float* xb = x + (size_t)b * XS + Gg;
  const float* w = Wd1 + (size_t)c * 2048;
  float s = 0.f;
  #pragma unroll
  for (int q = 0; q < 8; ++q) {
    int k = q * 256 + lane * 4;
    float4 xv = *(const float4*)(xb + k);
    float4 wv = *(const float4*)(w + k);
    s = fmaf(xv.x, wv.x, s);
    s = fmaf(xv.y, wv.y, s);
    s = fmaf(xv.z, wv.z, s);
    s = fmaf(xv.w, wv.w, s);
  }
  s = wred(s);
  __shared__ float y[16];
  if (lane == 0) y[b] = tanhf(s + bd1[c]);
  __syncthreads();
  if (tid < 16) {
    float S = 0.f, Q = 0.f;
    #pragma unroll
    for (int bb = 0; bb < 16; ++bb) { float v = y[bb]; S += v; Q += v * v; }
    float m = S * (1.0f / 16.0f), va = Q * (1.0f / 16.0f) - m * m;
    d1[tid * 100 + c] = (y[tid] - m) * rsqrtf(va + EPSf);
  }
}

// ---------------- K6: fused root term + drug layers 2-3 + final head ------
__global__ __launch_bounds__(512) void k_rootfinal(const float* __restrict__ rootin,
                                                   const float* __restrict__ d1,
                                                   const float* __restrict__ Wr1,
                                                   const float* __restrict__ br1,
                                                   const float* __restrict__ Wrc,
                                                   const float* __restrict__ brc,
                                                   const float* __restrict__ Wrd,
                                                   const float* __restrict__ brd,
                                                   const float* __restrict__ Wd2,
                                                   const float* __restrict__ bd2,
                                                   const float* __restrict__ Wd3,
                                                   const float* __restrict__ bd3,
                                                   const float* __restrict__ Wf,
                                                   const float* __restrict__ bf,
                                                   const float* __restrict__ Wfa,
                                                   const float* __restrict__ bfa,
                                                   const float* __restrict__ Wfo,
                                                   const float* __restrict__ bfo,
                                                   float* __restrict__ out) {
  const int tid = threadIdx.x;
  const int wv = tid >> 6, lane = tid & 63;
  __shared__ float r1[8][6], r2[8][6];
  __shared__ float w2s[50 * 101];
  __shared__ float d1s[1600];
  __shared__ float r2ds[96];
  for (int u = tid; u < 5000; u += 512) w2s[(u / 100) * 101 + (u % 100)] = Wd2[u];
  for (int u = tid; u < 1600; u += 512) d1s[u] = d1[u];

  // ---- root term ----
  const float* ci = rootin + (size_t)tid * 24;
  float cv[24];
  #pragma unroll
  for (int q = 0; q < 6; ++q) *(float4*)&cv[q * 4] = ((const float4*)ci)[q];
  float h[6];
  #pragma unroll
  for (int hh = 0; hh < 6; ++hh) {
    float s = br1[hh];
    #pragma unroll
    for (int i = 0; i < 24; ++i) s = fmaf(cv[i], Wr1[hh * 24 + i], s);
    h[hh] = s;
  }
  bn512(h, wv, lane, r1, r2);
  float c[6];
  #pragma unroll
  for (int k = 0; k < 6; ++k) {
    float s = brc[k];
    #pragma unroll
    for (int hh = 0; hh < 6; ++hh) s = fmaf(h[hh], Wrc[k * 6 + hh], s);
    c[k] = s;
  }
  bn512(c, wv, lane, r1, r2);
  float mv = (c[0] + c[1] + c[2] + c[3] + c[4] + c[5]) * (1.0f / 6.0f);
  __shared__ float shm[512];
  shm[tid] = mv;
  __syncthreads();
  __shared__ float st[96];
  if (tid < 96) {
    int b = tid / 6, hh = tid % 6;
    float s = brd[hh];
    #pragma unroll
    for (int e = 0; e < 32; ++e) s = fmaf(shm[b * 32 + e], Wrd[hh * 32 + e], s);
    st[tid] = tanhf(s);
  }
  __syncthreads();
  if (tid < 6) {
    float S = 0.f, Q = 0.f;
    for (int b = 0; b < 16; ++b) { float v = st[b * 6 + tid]; S += v; Q += v * v; }
    float m = S * (1.0f / 16.0f), va = Q * (1.0f / 16.0f) - m * m;
    float iv = rsqrtf(va + EPSf);
    for (int b = 0; b < 16; ++b) r2ds[b * 6 + tid] = (st[b * 6 + tid] - m) * iv;
  }
  __syncthreads();

  // ---- drug layers 2-3 + final head ----
  __shared__ float s2[800], mu2[50], iv2[50];
  for (int u = tid; u < 800; u += 512) {
    int b = u / 50, cc = u % 50;
    float s = bd2[cc];
    #pragma unroll
    for (int k = 0; k < 100; ++k) s = fmaf(d1s[b * 100 + k], w2s[cc * 101 + k], s);
    s2[u] = tanhf(s);
  }
  __syncthreads();
  if (tid < 50) {
    float S = 0.f, Q = 0.f;
    #pragma unroll
    for (int b = 0; b < 16; ++b) { float v = s2[b * 50 + tid]; S += v; Q += v * v; }
    float m = S * (1.0f / 16.0f), va = Q * (1.0f / 16.0f) - m * m;
    mu2[tid] = m; iv2[tid] = rsqrtf(va + EPSf);
  }
  __syncthreads();
  __shared__ float s3[96], mu3[6], iv3[6];
  if (tid < 96) {
    int b = tid / 6, cc = tid % 6;
    float s = bd3[cc];
    #pragma unroll
    for (int k = 0; k < 50; ++k)
      s = fmaf((s2[b * 50 + k] - mu2[k]) * iv2[k], Wd3[cc * 50 + k], s);
    s3[tid] = tanhf(s);
  }
  __syncthreads();
  if (tid < 6) {
    float S = 0.f, Q = 0.f;
    #pragma unroll
    for (int b = 0; b < 16; ++b) { float v = s3[b * 6 + tid]; S += v; Q += v * v; }
    float m = S * (1.0f / 16.0f), va = Q * (1.0f / 16.0f) - m * m;
    mu3[tid] = m; iv3[tid] = rsqrtf(va + EPSf);
  }
  __syncthreads();
  __shared__ float sf[96], muf[6], ivf[6];
  if (tid < 96) {
    int b = tid / 6, cc = tid % 6;
    float s = bf[cc];
    #pragma unroll
    for (int q = 0; q < 6; ++q) s = fmaf(r2ds[b * 6 + q], Wf[cc * 12 + q], s);
    #pragma unroll
    for (int q = 0; q < 6; ++q)
      s = fmaf((s3[b * 6 + q] - mu3[q]) * iv3[q], Wf[cc * 12 + 6 + q], s);
    sf[tid] = tanhf(s);
  }
  __syncthreads();
  if (tid < 6) {
    float S = 0.f, Q = 0.f;
    #pragma unroll
    for (int b = 0; b < 16; ++b) { float v = sf[b * 6 + tid]; S += v; Q += v * v; }
    float m = S * (1.0f / 16.0f), va = Q * (1.0f / 16.0f) - m * m;
    muf[tid] = m; ivf[tid] = rsqrtf(va + EPSf);
  }
  __syncthreads();
  if (tid < 16) {
    float s = bfa[0];
    #pragma unroll
    for (int q = 0; q < 6; ++q)
      s = fmaf((sf[tid * 6 + q] - muf[q]) * ivf[q], Wfa[q], s);
    float a = tanhf(s);
    out[tid] = a * Wfo[0] + bfo[0];
  }
}

extern "C" void kernel_launch(void* const* d_in, const int* in_sizes, int n_in,
                              void* d_out, int out_size, void* d_ws, size_t ws_size,
                              hipStream_t stream) {
  const float* x     = (const float*)d_in[0];
  const int*   table = (const int*)d_in[1];
  const float* Wrbf  = (const float*)d_in[2];
  const float* brbf  = (const float*)d_in[3];
  const float* emb   = (const float*)d_in[4];
  const float* Wdg   = (const float*)d_in[5];
  const float* bdg   = (const float*)d_in[6];
  const float* Wl1   = (const float*)d_in[7];
  const float* bl1   = (const float*)d_in[8];
  const float* Wlc   = (const float*)d_in[9];
  const float* blc   = (const float*)d_in[10];
  const float* Wm1   = (const float*)d_in[13];
  const float* bm1   = (const float*)d_in[14];
  const float* Wmc   = (const float*)d_in[15];
  const float* bmc   = (const float*)d_in[16];
  const float* Wr1   = (const float*)d_in[19];
  const float* br1   = (const float*)d_in[20];
  const float* Wrc   = (const float*)d_in[21];
  const float* brc   = (const float*)d_in[22];
  const float* Wrd   = (const float*)d_in[23];
  const float* brd   = (const float*)d_in[24];
  const float* Wd1   = (const float*)d_in[25];
  const float* bd1   = (const float*)d_in[26];
  const float* Wd2   = (const float*)d_in[27];
  const float* bd2   = (const float*)d_in[28];
  const float* Wd3   = (const float*)d_in[29];
  const float* bd3   = (const float*)d_in[30];
  const float* Wf    = (const float*)d_in[31];
  const float* bf    = (const float*)d_in[32];
  const float* Wfa   = (const float*)d_in[33];
  const float* bfa   = (const float*)d_in[34];
  const float* Wfo   = (const float*)d_in[35];
  const float* bfo   = (const float*)d_in[36];
  float* out = (float*)d_out;

  u32* Rhi = (u32*)d_ws;                   // 32768
  u32* Rlo = Rhi + 32768;                  // 32768
  u32* Dhi = Rlo + 32768;                  // 1048576
  u32* Dlo = Dhi + 1048576;                // 1048576
  u32* Ahi = Dlo + 1048576;                // 524288
  u32* Alo = Ahi + 524288;                 // 524288
  float* partB = (float*)(Alo + 524288);   // 4 * 524288
  float* midin = partB + 4 * 524288;       // 49152
  float* rootin= midin + 49152;            // 12288
  float* d1    = rootin + 12288;           // 1600

  hipLaunchKernelGGL(k_drug1,     dim3(100),    dim3(1024), 0, stream, x, Wd1, bd1, d1);
  hipLaunchKernelGGL(k_split,     dim3(1056),   dim3(256),  0, stream, Wrbf, Wdg, Rhi, Rlo, Dhi, Dlo);
  hipLaunchKernelGGL(k_rbf2,      dim3(32, 16), dim3(1024), 0, stream, x, Rhi, Rlo, table, emb, brbf, Ahi, Alo);
  hipLaunchKernelGGL(k_mm,        dim3(256),    dim3(512),  0, stream, Ahi, Alo, Dhi, Dlo, partB);
  hipLaunchKernelGGL(k_leaf,      dim3(16),     dim3(512),  0, stream, partB, bdg, Wl1, bl1, Wlc, blc, midin);
  hipLaunchKernelGGL(k_mid,       dim3(4),      dim3(512),  0, stream, midin, Wm1, bm1, Wmc, bmc, rootin);
  hipLaunchKernelGGL(k_rootfinal, dim3(1),      dim3(512),  0, stream, rootin, d1,
                     Wr1, br1, Wrc, brc, Wrd, brd, Wd2, bd2, Wd3, bd3,
                     Wf, bf, Wfa, bfa, Wfo, bfo, out);
}

// Round 10
// 104.531 us; speedup vs baseline: 1.2085x; 1.1056x over previous
//
#include <hip/hip_runtime.h>
#include <hip/hip_bf16.h>

// Sizes
#define Bb 16
#define Gg 2048
#define Dd 2048
#define XS 4097   // G + D + 1
#define EPSf 1e-5f
#define CEXP (-0.72134752044448170368f)   // -gamma * log2(e), gamma = 0.5

typedef unsigned int u32;
typedef __attribute__((ext_vector_type(8))) short bf16x8;
typedef __attribute__((ext_vector_type(4))) float f32x4;

union U16 { uint4 u; bf16x8 v; };

__device__ inline float fast_exp2(float x) {
#if __has_builtin(__builtin_amdgcn_exp2f)
  return __builtin_amdgcn_exp2f(x);
#else
  return exp2f(x);
#endif
}

// pack two f32 into one u32 of 2 bf16 (truncation): low half from a, high from b
__device__ inline u32 pk2(float a, float b) {
  return __builtin_amdgcn_perm(__float_as_uint(b), __float_as_uint(a), 0x07060302u);
}
__device__ inline float bftrunc(float a) {
  return __uint_as_float(__float_as_uint(a) & 0xFFFF0000u);
}

// split 8 floats into hi/lo bf16x8 fragments
__device__ inline void split8(const float* f, U16& hi, U16& lo) {
  u32 h[4], l[4];
  #pragma unroll
  for (int p = 0; p < 4; ++p) {
    float a = f[2 * p], b = f[2 * p + 1];
    h[p] = pk2(a, b);
    l[p] = pk2(a - bftrunc(a), b - bftrunc(b));
  }
  hi.u = make_uint4(h[0], h[1], h[2], h[3]);
  lo.u = make_uint4(l[0], l[1], l[2], l[3]);
}

__device__ inline float wred(float v) {
  #pragma unroll
  for (int o = 32; o > 0; o >>= 1) v += __shfl_xor(v, o, 64);
  return v;
}

// ---------------- K0: merged drug layer 1 + weight split ------------------
// blocks 0..99: drug1 (1024 thr). blocks 100..363: split (264*1024 = 270336).
__global__ __launch_bounds__(1024) void k_pre(const float* __restrict__ x,
                                              const float* __restrict__ Wd1,
                                              const float* __restrict__ bd1,
                                              float* __restrict__ d1,
                                              const float* __restrict__ Wrbf,
                                              const float* __restrict__ Wdg,
                                              u32* __restrict__ Rhi, u32* __restrict__ Rlo,
                                              u32* __restrict__ Dhi, u32* __restrict__ Dlo) {
  const int tid = threadIdx.x;
  if (blockIdx.x < 100) {
    const int c = blockIdx.x;
    const int b = tid >> 6, lane = tid & 63;
    const float* xb = x + (size_t)b * XS + Gg;
    const float* w = Wd1 + (size_t)c * 2048;
    float s = 0.f;
    #pragma unroll
    for (int q = 0; q < 8; ++q) {
      int k = q * 256 + lane * 4;
      float4 xv = *(const float4*)(xb + k);
      float4 wv = *(const float4*)(w + k);
      s = fmaf(xv.x, wv.x, s);
      s = fmaf(xv.y, wv.y, s);
      s = fmaf(xv.z, wv.z, s);
      s = fmaf(xv.w, wv.w, s);
    }
    s = wred(s);
    __shared__ float y[16];
    if (lane == 0) y[b] = tanhf(s + bd1[c]);
    __syncthreads();
    if (tid < 16) {
      float S = 0.f, Q = 0.f;
      #pragma unroll
      for (int bb = 0; bb < 16; ++bb) { float v = y[bb]; S += v; Q += v * v; }
      float m = S * (1.0f / 16.0f), va = Q * (1.0f / 16.0f) - m * m;
      d1[tid * 100 + c] = (y[tid] - m) * rsqrtf(va + EPSf);
    }
  } else {
    int c = (blockIdx.x - 100) * 1024 + tid;   // 0..270335
    const float* src;
    u32 *dhi, *dlo;
    if (c < 8192) {
      int h = c >> 12, ks = (c >> 6) & 63, l = c & 63;
      src = Wrbf + (h * 16 + (l & 15)) * Gg + ks * 32 + (l >> 4) * 8;
      dhi = Rhi + (size_t)c * 4; dlo = Rlo + (size_t)c * 4;
    } else {
      int cc = c - 8192;
      int nf = cc >> 12, ks = (cc >> 6) & 63, l = cc & 63;
      src = Wdg + (size_t)(nf * 16 + (l & 15)) * Gg + ks * 32 + (l >> 4) * 8;
      dhi = Dhi + (size_t)cc * 4; dlo = Dlo + (size_t)cc * 4;
    }
    float4 f0 = *(const float4*)src;
    float4 f1 = *(const float4*)(src + 4);
    float f[8] = {f0.x, f0.y, f0.z, f0.w, f1.x, f1.y, f1.z, f1.w};
    U16 hi, lo;
    split8(f, hi, lo);
    *(uint4*)dhi = hi.u;
    *(uint4*)dlo = lo.u;
  }
}

// ---------------- K1: fused RBF einsum + pack, LDS weight staging ---------
// grid (32 i-tiles of 64, 16 b), 1024 thr = 16 waves.
// compute role: wave w = (isub = w>>2, jcw = w&3).
// staging role:  wave w = (jcw_s = w>>2, arr2_s = w&3); per ksl each wave
// stages one 1KB tensor slice (ks = jcw_s*16+ksl) into w_s double buffer.
// red[] aliases w_s (disjoint phases, barrier separated).
__global__ __launch_bounds__(1024) void k_rbf3(const float* __restrict__ x,
                                               const u32* __restrict__ Whi,
                                               const u32* __restrict__ Wlo,
                                               const int* __restrict__ table,
                                               const float* __restrict__ emb,
                                               const float* __restrict__ brbf,
                                               u32* __restrict__ Ahi,
                                               u32* __restrict__ Alo) {
  __shared__ float g_s[2048];
  __shared__ u32 w_s[2][16][256];   // 32KB; aliased as red[16][64][8] later
  float (*red)[64][8] = (float (*)[64][8]) & w_s[0][0][0];
  const int tid = threadIdx.x;
  const int lane = tid & 63, wid = tid >> 6;
  const int isub = wid >> 2, jcw = wid & 3;
  const int i0 = blockIdx.x * 64, b = blockIdx.y;
  const int i0w = i0 + isub * 16;
  g_s[tid] = x[(size_t)b * XS + tid];
  g_s[tid + 1024] = x[(size_t)b * XS + 1024 + tid];
  const float gi = x[(size_t)b * XS + i0w + (lane & 15)];
  f32x4 acc0 = {0.f, 0.f, 0.f, 0.f};
  f32x4 acc1 = {0.f, 0.f, 0.f, 0.f};
  const int jb = (lane >> 4) * 8;

  // staging role
  const int jcw_s = wid >> 2, arr2_s = wid & 3;
  const u32* wsrc = ((arr2_s & 2) ? Wlo : Whi) + ((arr2_s & 1) ? 16384 : 0);
  uint4 pf = *(const uint4*)(wsrc + ((size_t)(jcw_s * 16)) * 256 + lane * 4);

  for (int ksl = 0; ksl < 16; ++ksl) {
    *(uint4*)&w_s[ksl & 1][wid][lane * 4] = pf;
    if (ksl < 15)
      pf = *(const uint4*)(wsrc + ((size_t)(jcw_s * 16 + ksl + 1)) * 256 + lane * 4);
    __syncthreads();   // staged writes visible (also covers g_s on iter 0)
    const int ks = jcw * 16 + ksl;
    const float* gp = &g_s[ks * 32 + jb];
    float4 gja = *(const float4*)gp;
    float4 gjb = *(const float4*)(gp + 4);
    float gv[8] = {gja.x, gja.y, gja.z, gja.w, gjb.x, gjb.y, gjb.z, gjb.w};
    float kv[8];
    #pragma unroll
    for (int q = 0; q < 8; ++q) {
      float d = gi - gv[q];
      kv[q] = fast_exp2(d * d * CEXP);
    }
    U16 ah, al;
    split8(kv, ah, al);
    U16 w0h, w1h, w0l, w1l;
    w0h.u = *(const uint4*)&w_s[ksl & 1][jcw * 4 + 0][lane * 4];
    w1h.u = *(const uint4*)&w_s[ksl & 1][jcw * 4 + 1][lane * 4];
    w0l.u = *(const uint4*)&w_s[ksl & 1][jcw * 4 + 2][lane * 4];
    w1l.u = *(const uint4*)&w_s[ksl & 1][jcw * 4 + 3][lane * 4];
    acc0 = __builtin_amdgcn_mfma_f32_16x16x32_bf16(ah.v, w0h.v, acc0, 0, 0, 0);
    acc0 = __builtin_amdgcn_mfma_f32_16x16x32_bf16(al.v, w0h.v, acc0, 0, 0, 0);
    acc0 = __builtin_amdgcn_mfma_f32_16x16x32_bf16(ah.v, w0l.v, acc0, 0, 0, 0);
    acc1 = __builtin_amdgcn_mfma_f32_16x16x32_bf16(ah.v, w1h.v, acc1, 0, 0, 0);
    acc1 = __builtin_amdgcn_mfma_f32_16x16x32_bf16(al.v, w1h.v, acc1, 0, 0, 0);
    acc1 = __builtin_amdgcn_mfma_f32_16x16x32_bf16(ah.v, w1l.v, acc1, 0, 0, 0);
  }
  __syncthreads();   // all w_s reads done before red aliases it
  #pragma unroll
  for (int k = 0; k < 4; ++k) { red[wid][lane][k] = acc0[k]; red[wid][lane][4 + k] = acc1[k]; }
  __syncthreads();
  if (jcw == 0) {
    float f[8];
    #pragma unroll
    for (int k = 0; k < 8; ++k)
      f[k] = red[isub * 4][lane][k] + red[isub * 4 + 1][lane][k] +
             red[isub * 4 + 2][lane][k] + red[isub * 4 + 3][lane][k];
    const int idx = (int)x[(size_t)b * XS + Gg + Dd];
    const int eloc = lane & 15, quad = lane >> 4;
    const int ib = i0w + quad * 4;
    int4 tt = *(const int4*)&table[(size_t)idx * Gg + ib];
    const int ks = i0w >> 5;
    const int lp = (2 * ((i0w >> 4) & 1) + (quad >> 1)) * 16 + eloc;
    const int hs = quad & 1;
    #pragma unroll
    for (int hb = 0; hb < 2; ++hb) {
      const int e = hb * 16 + eloc;
      const float bias = brbf[e];
      float v0 = f[hb * 4 + 0] + bias + emb[tt.x * 32 + e];
      float v1 = f[hb * 4 + 1] + bias + emb[tt.y * 32 + e];
      float v2 = f[hb * 4 + 2] + bias + emb[tt.z * 32 + e];
      float v3 = f[hb * 4 + 3] + bias + emb[tt.w * 32 + e];
      size_t off = (((size_t)(b * 2 + hb) * 64 + ks) * 64 + lp) * 4 + hs * 2;
      Ahi[off]     = pk2(v0, v1);
      Ahi[off + 1] = pk2(v2, v3);
      Alo[off]     = pk2(v0 - bftrunc(v0), v1 - bftrunc(v1));
      Alo[off + 1] = pk2(v2 - bftrunc(v2), v3 - bftrunc(v3));
    }
  }
}

// ---------------- K2: gene GEMM 512x1024x2048, split-bf16 MFMA ------------
// 256 blocks x 512 threads (8 waves, 2x4): BM=64 (by), BN=128 (bx), kc=4.
// (R7/R9-verified version.) partB layout [kc][n][m].
__global__ __launch_bounds__(512) void k_mm(const u32* __restrict__ Ahi,
                                            const u32* __restrict__ Alo,
                                            const u32* __restrict__ Bhi,
                                            const u32* __restrict__ Blo,
                                            float* __restrict__ part) {
  __shared__ u32 s_mm[6144];   // 24 segs x 1KB
  const int tid = threadIdx.x;
  const int lane = tid & 63, wid = tid >> 6;   // 8 waves
  const int id = blockIdx.x;
  const int pl = id & 7, by = (id >> 3) & 7, ph = id >> 6;
  const int p = ph * 8 + pl;
  const int bx = p >> 2, kc = p & 3;
  const int wm = wid >> 2, wn = wid & 3;       // 2 x 4 waves
  f32x4 acc[2][2];
  #pragma unroll
  for (int mf = 0; mf < 2; ++mf)
    #pragma unroll
    for (int nf = 0; nf < 2; ++nf) acc[mf][nf] = (f32x4){0.f, 0.f, 0.f, 0.f};

  uint4 pf[3];
  #pragma unroll
  for (int q = 0; q < 3; ++q) {
    int seg = wid * 3 + q;
    const u32* src;
    if (seg < 8) {
      int hl = seg >> 2, mf = seg & 3;
      src = (hl ? Alo : Ahi) + (((size_t)(by * 4 + mf) * 64 + kc * 16) * 64 + lane) * 4;
    } else {
      int t = seg - 8, hl = t >> 3, nf = t & 7;
      src = (hl ? Blo : Bhi) + (((size_t)(bx * 8 + nf) * 64 + kc * 16) * 64 + lane) * 4;
    }
    pf[q] = *(const uint4*)src;
  }
  for (int stage = 0; stage < 16; ++stage) {
    __syncthreads();
    #pragma unroll
    for (int q = 0; q < 3; ++q)
      *(uint4*)&s_mm[(wid * 3 + q) * 256 + lane * 4] = pf[q];
    if (stage < 15) {
      const int ks = kc * 16 + stage + 1;
      #pragma unroll
      for (int q = 0; q < 3; ++q) {
        int seg = wid * 3 + q;
        const u32* src;
        if (seg < 8) {
          int hl = seg >> 2, mf = seg & 3;
          src = (hl ? Alo : Ahi) + (((size_t)(by * 4 + mf) * 64 + ks) * 64 + lane) * 4;
        } else {
          int t = seg - 8, hl = t >> 3, nf = t & 7;
          src = (hl ? Blo : Bhi) + (((size_t)(bx * 8 + nf) * 64 + ks) * 64 + lane) * 4;
        }
        pf[q] = *(const uint4*)src;
      }
    }
    __syncthreads();
    U16 ah[2], al[2], bh[2], bl[2];
    #pragma unroll
    for (int mf = 0; mf < 2; ++mf) {
      ah[mf].u = *(const uint4*)&s_mm[(0 + wm * 2 + mf) * 256 + lane * 4];
      al[mf].u = *(const uint4*)&s_mm[(4 + wm * 2 + mf) * 256 + lane * 4];
    }
    #pragma unroll
    for (int nf = 0; nf < 2; ++nf) {
      bh[nf].u = *(const uint4*)&s_mm[(8 + wn * 2 + nf) * 256 + lane * 4];
      bl[nf].u = *(const uint4*)&s_mm[(16 + wn * 2 + nf) * 256 + lane * 4];
    }
    #pragma unroll
    for (int mf = 0; mf < 2; ++mf) {
      #pragma unroll
      for (int nf = 0; nf < 2; ++nf) {
        acc[mf][nf] = __builtin_amdgcn_mfma_f32_16x16x32_bf16(ah[mf].v, bh[nf].v, acc[mf][nf], 0, 0, 0);
        acc[mf][nf] = __builtin_amdgcn_mfma_f32_16x16x32_bf16(al[mf].v, bh[nf].v, acc[mf][nf], 0, 0, 0);
        acc[mf][nf] = __builtin_amdgcn_mfma_f32_16x16x32_bf16(ah[mf].v, bl[nf].v, acc[mf][nf], 0, 0, 0);
      }
    }
  }
  const int quad = lane >> 4, nl = lane & 15;
  #pragma unroll
  for (int mf = 0; mf < 2; ++mf) {
    #pragma unroll
    for (int nf = 0; nf < 2; ++nf) {
      int n  = bx * 128 + wn * 32 + nf * 16 + nl;
      int m0 = by * 64 + wm * 32 + mf * 16 + quad * 4;
      float4 st = make_float4(acc[mf][nf][0], acc[mf][nf][1], acc[mf][nf][2], acc[mf][nf][3]);
      *(float4*)&part[(size_t)kc * 524288 + (size_t)n * 512 + m0] = st;
    }
  }
}

// ---------------- batchnorm over 512 threads, 6 channels -----------------
__device__ inline void bn512(float* v, int wv, int lane,
                             float (*r1)[6], float (*r2)[6]) {
  float s[6], q[6];
  #pragma unroll
  for (int c = 0; c < 6; ++c) {
    float a = v[c];
    s[c] = wred(a);
    q[c] = wred(a * a);
  }
  __syncthreads();
  if (lane == 0) {
    #pragma unroll
    for (int c = 0; c < 6; ++c) { r1[wv][c] = s[c]; r2[wv][c] = q[c]; }
  }
  __syncthreads();
  #pragma unroll
  for (int c = 0; c < 6; ++c) {
    float S = 0.f, Q = 0.f;
    #pragma unroll
    for (int w = 0; w < 8; ++w) { S += r1[w][c]; Q += r2[w][c]; }
    float m  = S * (1.0f / 512.0f);
    float va = Q * (1.0f / 512.0f) - m * m;
    v[c] = (v[c] - m) * rsqrtf(va + EPSf);
  }
}

// ---------------- K3a: leaf partial-h (spread the partB read) -------------
// grid (8 ic, 16 l), 512 thr (tid = m = b*32+e). Each block: 8 n-rows.
// hpart[(l*8+ic)*512 + m][6]
__global__ __launch_bounds__(512) void k_leafA(const float* __restrict__ part,
                                               const float* __restrict__ bdg,
                                               const float* __restrict__ W1,
                                               float* __restrict__ hpart) {
  const int ic = blockIdx.x, l = blockIdx.y, tid = threadIdx.x;
  const float* w1 = W1 + l * 384;
  float hp[6] = {0.f, 0.f, 0.f, 0.f, 0.f, 0.f};
  #pragma unroll
  for (int r = 0; r < 8; ++r) {
    int i = ic * 8 + r;
    int n = l * 64 + i;
    const float* pp = part + (size_t)n * 512 + tid;
    float cv = pp[0] + pp[524288] + pp[2 * 524288] + pp[3 * 524288] + bdg[n];
    #pragma unroll
    for (int hh = 0; hh < 6; ++hh) hp[hh] = fmaf(cv, w1[hh * 64 + i], hp[hh]);
  }
  float* o = hpart + ((size_t)(l * 8 + ic) * 512 + tid) * 6;
  #pragma unroll
  for (int hh = 0; hh < 6; ++hh) o[hh] = hp[hh];
}

// ---------------- K3b: leaf finish (sum partials + bn + c + bn) -----------
__global__ __launch_bounds__(512) void k_leafB(const float* __restrict__ hpart,
                                               const float* __restrict__ b1,
                                               const float* __restrict__ Wc,
                                               const float* __restrict__ bc,
                                               float* __restrict__ outp) {
  const int l = blockIdx.x, tid = threadIdx.x;
  const int wv = tid >> 6, lane = tid & 63;
  __shared__ float r1[8][6], r2[8][6];
  float h[6];
  #pragma unroll
  for (int hh = 0; hh < 6; ++hh) h[hh] = b1[l * 6 + hh];
  #pragma unroll
  for (int ic = 0; ic < 8; ++ic) {
    const float* hp = hpart + ((size_t)(l * 8 + ic) * 512 + tid) * 6;
    #pragma unroll
    for (int hh = 0; hh < 6; ++hh) h[hh] += hp[hh];
  }
  bn512(h, wv, lane, r1, r2);
  float c[6];
  #pragma unroll
  for (int k = 0; k < 6; ++k) {
    float s = bc[l * 6 + k];
    #pragma unroll
    for (int hh = 0; hh < 6; ++hh) s = fmaf(h[hh], Wc[l * 36 + k * 6 + hh], s);
    c[k] = s;
  }
  bn512(c, wv, lane, r1, r2);
  float* o = outp + (((size_t)(l >> 2) * 512 + tid) * 24 + (l & 3) * 6);
  #pragma unroll
  for (int k = 0; k < 6; ++k) o[k] = c[k];
}

// ---------------- K4: mid term --------------------------------------------
__global__ __launch_bounds__(512) void k_mid(const float* __restrict__ gin,
                                             const float* __restrict__ W1,
                                             const float* __restrict__ b1,
                                             const float* __restrict__ Wc,
                                             const float* __restrict__ bc,
                                             float* __restrict__ outp) {
  const int l = blockIdx.x, tid = threadIdx.x;
  const int wv = tid >> 6, lane = tid & 63;
  __shared__ float r1[8][6], r2[8][6];
  const float* ci = gin + ((size_t)l * 512 + tid) * 24;
  float cv[24];
  #pragma unroll
  for (int q = 0; q < 6; ++q) *(float4*)&cv[q * 4] = ((const float4*)ci)[q];
  const float* w1 = W1 + l * 6 * 24;
  float h[6];
  #pragma unroll
  for (int hh = 0; hh < 6; ++hh) {
    float s = b1[l * 6 + hh];
    #pragma unroll
    for (int i = 0; i < 24; ++i) s = fmaf(cv[i], w1[hh * 24 + i], s);
    h[hh] = s;
  }
  bn512(h, wv, lane, r1, r2);
  float c[6];
  #pragma unroll
  for (int k = 0; k < 6; ++k) {
    float s = bc[l * 6 + k];
    #pragma unroll
    for (int hh = 0; hh < 6; ++hh) s = fmaf(h[hh], Wc[l * 36 + k * 6 + hh], s);
    c[k] = s;
  }
  bn512(c, wv, lane, r1, r2);
  float* o = outp + ((size_t)tid * 24 + l * 6);
  #pragma unroll
  for (int k = 0; k < 6; ++k) o[k] = c[k];
}

// ---------------- K5: fused root term + drug layers 2-3 + final head ------
__global__ __launch_bounds__(512) void k_rootfinal(const float* __restrict__ rootin,
                                                   const float* __restrict__ d1,
                                                   const float* __restrict__ Wr1,
                                                   const float* __restrict__ br1,
                                                   const float* __restrict__ Wrc,
                                                   const float* __restrict__ brc,
                                                   const float* __restrict__ Wrd,
                                                   const float* __restrict__ brd,
                                                   const float* __restrict__ Wd2,
                                                   const float* __restrict__ bd2,
                                                   const float* __restrict__ Wd3,
                                                   const float* __restrict__ bd3,
                                                   const float* __restrict__ Wf,
                                                   const float* __restrict__ bf,
                                                   const float* __restrict__ Wfa,
                                                   const float* __restrict__ bfa,
                                                   const float* __restrict__ Wfo,
                                                   const float* __restrict__ bfo,
                                                   float* __restrict__ out) {
  const int tid = threadIdx.x;
  const int wv = tid >> 6, lane = tid & 63;
  __shared__ float r1[8][6], r2[8][6];
  __shared__ float w2s[50 * 101];
  __shared__ float d1s[1600];
  __shared__ float r2ds[96];
  for (int u = tid; u < 5000; u += 512) w2s[(u / 100) * 101 + (u % 100)] = Wd2[u];
  for (int u = tid; u < 1600; u += 512) d1s[u] = d1[u];

  // ---- root term ----
  const float* ci = rootin + (size_t)tid * 24;
  float cv[24];
  #pragma unroll
  for (int q = 0; q < 6; ++q) *(float4*)&cv[q * 4] = ((const float4*)ci)[q];
  float h[6];
  #pragma unroll
  for (int hh = 0; hh < 6; ++hh) {
    float s = br1[hh];
    #pragma unroll
    for (int i = 0; i < 24; ++i) s = fmaf(cv[i], Wr1[hh * 24 + i], s);
    h[hh] = s;
  }
  bn512(h, wv, lane, r1, r2);
  float c[6];
  #pragma unroll
  for (int k = 0; k < 6; ++k) {
    float s = brc[k];
    #pragma unroll
    for (int hh = 0; hh < 6; ++hh) s = fmaf(h[hh], Wrc[k * 6 + hh], s);
    c[k] = s;
  }
  bn512(c, wv, lane, r1, r2);
  float mv = (c[0] + c[1] + c[2] + c[3] + c[4] + c[5]) * (1.0f / 6.0f);
  __shared__ float shm[512];
  shm[tid] = mv;
  __syncthreads();
  __shared__ float st[96];
  if (tid < 96) {
    int b = tid / 6, hh = tid % 6;
    float s = brd[hh];
    #pragma unroll
    for (int e = 0; e < 32; ++e) s = fmaf(shm[b * 32 + e], Wrd[hh * 32 + e], s);
    st[tid] = tanhf(s);
  }
  __syncthreads();
  if (tid < 6) {
    float S = 0.f, Q = 0.f;
    for (int b = 0; b < 16; ++b) { float v = st[b * 6 + tid]; S += v; Q += v * v; }
    float m = S * (1.0f / 16.0f), va = Q * (1.0f / 16.0f) - m * m;
    float iv = rsqrtf(va + EPSf);
    for (int b = 0; b < 16; ++b) r2ds[b * 6 + tid] = (st[b * 6 + tid] - m) * iv;
  }
  __syncthreads();

  // ---- drug layers 2-3 + final head ----
  __shared__ float s2[800], mu2[50], iv2[50];
  for (int u = tid; u < 800; u += 512) {
    int b = u / 50, cc = u % 50;
    float s = bd2[cc];
    #pragma unroll
    for (int k = 0; k < 100; ++k) s = fmaf(d1s[b * 100 + k], w2s[cc * 101 + k], s);
    s2[u] = tanhf(s);
  }
  __syncthreads();
  if (tid < 50) {
    float S = 0.f, Q = 0.f;
    #pragma unroll
    for (int b = 0; b < 16; ++b) { float v = s2[b * 50 + tid]; S += v; Q += v * v; }
    float m = S * (1.0f / 16.0f), va = Q * (1.0f / 16.0f) - m * m;
    mu2[tid] = m; iv2[tid] = rsqrtf(va + EPSf);
  }
  __syncthreads();
  __shared__ float s3[96], mu3[6], iv3[6];
  if (tid < 96) {
    int b = tid / 6, cc = tid % 6;
    float s = bd3[cc];
    #pragma unroll
    for (int k = 0; k < 50; ++k)
      s = fmaf((s2[b * 50 + k] - mu2[k]) * iv2[k], Wd3[cc * 50 + k], s);
    s3[tid] = tanhf(s);
  }
  __syncthreads();
  if (tid < 6) {
    float S = 0.f, Q = 0.f;
    #pragma unroll
    for (int b = 0; b < 16; ++b) { float v = s3[b * 6 + tid]; S += v; Q += v * v; }
    float m = S * (1.0f / 16.0f), va = Q * (1.0f / 16.0f) - m * m;
    mu3[tid] = m; iv3[tid] = rsqrtf(va + EPSf);
  }
  __syncthreads();
  __shared__ float sf[96], muf[6], ivf[6];
  if (tid < 96) {
    int b = tid / 6, cc = tid % 6;
    float s = bf[cc];
    #pragma unroll
    for (int q = 0; q < 6; ++q) s = fmaf(r2ds[b * 6 + q], Wf[cc * 12 + q], s);
    #pragma unroll
    for (int q = 0; q < 6; ++q)
      s = fmaf((s3[b * 6 + q] - mu3[q]) * iv3[q], Wf[cc * 12 + 6 + q], s);
    sf[tid] = tanhf(s);
  }
  __syncthreads();
  if (tid < 6) {
    float S = 0.f, Q = 0.f;
    #pragma unroll
    for (int b = 0; b < 16; ++b) { float v = sf[b * 6 + tid]; S += v; Q += v * v; }
    float m = S * (1.0f / 16.0f), va = Q * (1.0f / 16.0f) - m * m;
    muf[tid] = m; ivf[tid] = rsqrtf(va + EPSf);
  }
  __syncthreads();
  if (tid < 16) {
    float s = bfa[0];
    #pragma unroll
    for (int q = 0; q < 6; ++q)
      s = fmaf((sf[tid * 6 + q] - muf[q]) * ivf[q], Wfa[q], s);
    float a = tanhf(s);
    out[tid] = a * Wfo[0] + bfo[0];
  }
}

extern "C" void kernel_launch(void* const* d_in, const int* in_sizes, int n_in,
                              void* d_out, int out_size, void* d_ws, size_t ws_size,
                              hipStream_t stream) {
  const float* x     = (const float*)d_in[0];
  const int*   table = (const int*)d_in[1];
  const float* Wrbf  = (const float*)d_in[2];
  const float* brbf  = (const float*)d_in[3];
  const float* emb   = (const float*)d_in[4];
  const float* Wdg   = (const float*)d_in[5];
  const float* bdg   = (const float*)d_in[6];
  const float* Wl1   = (const float*)d_in[7];
  const float* bl1   = (const float*)d_in[8];
  const float* Wlc   = (const float*)d_in[9];
  const float* blc   = (const float*)d_in[10];
  const float* Wm1   = (const float*)d_in[13];
  const float* bm1   = (const float*)d_in[14];
  const float* Wmc   = (const float*)d_in[15];
  const float* bmc   = (const float*)d_in[16];
  const float* Wr1   = (const float*)d_in[19];
  const float* br1   = (const float*)d_in[20];
  const float* Wrc   = (const float*)d_in[21];
  const float* brc   = (const float*)d_in[22];
  const float* Wrd   = (const float*)d_in[23];
  const float* brd   = (const float*)d_in[24];
  const float* Wd1   = (const float*)d_in[25];
  const float* bd1   = (const float*)d_in[26];
  const float* Wd2   = (const float*)d_in[27];
  const float* bd2   = (const float*)d_in[28];
  const float* Wd3   = (const float*)d_in[29];
  const float* bd3   = (const float*)d_in[30];
  const float* Wf    = (const float*)d_in[31];
  const float* bf    = (const float*)d_in[32];
  const float* Wfa   = (const float*)d_in[33];
  const float* bfa   = (const float*)d_in[34];
  const float* Wfo   = (const float*)d_in[35];
  const float* bfo   = (const float*)d_in[36];
  float* out = (float*)d_out;

  u32* Rhi = (u32*)d_ws;                   // 32768
  u32* Rlo = Rhi + 32768;                  // 32768
  u32* Dhi = Rlo + 32768;                  // 1048576
  u32* Dlo = Dhi + 1048576;                // 1048576
  u32* Ahi = Dlo + 1048576;                // 524288
  u32* Alo = Ahi + 524288;                 // 524288
  float* partB = (float*)(Alo + 524288);   // 4 * 524288
  float* hpart = partB + 4 * 524288;       // 393216
  float* midin = hpart + 393216;           // 49152
  float* rootin= midin + 49152;            // 12288
  float* d1    = rootin + 12288;           // 1600

  hipLaunchKernelGGL(k_pre,       dim3(364),    dim3(1024), 0, stream,
                     x, Wd1, bd1, d1, Wrbf, Wdg, Rhi, Rlo, Dhi, Dlo);
  hipLaunchKernelGGL(k_rbf3,      dim3(32, 16), dim3(1024), 0, stream,
                     x, Rhi, Rlo, table, emb, brbf, Ahi, Alo);
  hipLaunchKernelGGL(k_mm,        dim3(256),    dim3(512),  0, stream, Ahi, Alo, Dhi, Dlo, partB);
  hipLaunchKernelGGL(k_leafA,     dim3(8, 16),  dim3(512),  0, stream, partB, bdg, Wl1, hpart);
  hipLaunchKernelGGL(k_leafB,     dim3(16),     dim3(512),  0, stream, hpart, bl1, Wlc, blc, midin);
  hipLaunchKernelGGL(k_mid,       dim3(4),      dim3(512),  0, stream, midin, Wm1, bm1, Wmc, bmc, rootin);
  hipLaunchKernelGGL(k_rootfinal, dim3(1),      dim3(512),  0, stream, rootin, d1,
                     Wr1, br1, Wrc, brc, Wrd, brd, Wd2, bd2, Wd3, bd3,
                     Wf, bf, Wfa, bfa, Wfo, bfo, out);
}